// Round 1
// baseline (2302.522 us; speedup 1.0000x reference)
//
#include <hip/hip_runtime.h>
#include <stdint.h>

#define PN 4
#define NN 65536
#define DD 128
#define OO 128
#define EE 500000
#define MM 32768

typedef __attribute__((ext_vector_type(8))) short short8;
typedef __attribute__((ext_vector_type(4))) float floatx4;

__device__ __forceinline__ unsigned short f2bf(float f) {
  unsigned u = __float_as_uint(f);
  u += 0x7fffu + ((u >> 16) & 1u);
  return (unsigned short)(u >> 16);
}
__device__ __forceinline__ float bfhi2f(unsigned u) { return __uint_as_float(u & 0xffff0000u); }
__device__ __forceinline__ float bflo2f(unsigned u) { return __uint_as_float(u << 16); }

// block b = s*4+d; diag blocks are b in {0,5,10,15}
__device__ __forceinline__ long rowbase(int b) {
  int diagb = (b + 4) / 5;   // diag blocks strictly before b
  int offb = b - diagb;      // off-diag blocks strictly before b
  return (long)diagb * NN + (long)offb * MM;
}

// ---- fp32 -> bf16 conversion of feats (one thread per 4 floats) ----
__global__ __launch_bounds__(256) void cvt_kernel(const float* __restrict__ f,
                                                  unsigned short* __restrict__ o) {
  size_t i = (size_t)blockIdx.x * blockDim.x + threadIdx.x;
  float4 v = ((const float4*)f)[i];
  uint2 r;
  r.x = ((unsigned)f2bf(v.y) << 16) | f2bf(v.x);
  r.y = ((unsigned)f2bf(v.w) << 16) | f2bf(v.z);
  ((uint2*)o)[i] = r;
}

// ---- in-degree histogram ----
__global__ __launch_bounds__(256) void hist_kernel(const int* __restrict__ edst,
                                                   int* __restrict__ deg) {
  int b = blockIdx.y;
  int e = blockIdx.x * blockDim.x + threadIdx.x;
  if (e >= EE) return;
  int dv = edst[(size_t)b * EE + e];
  atomicAdd(&deg[b * NN + dv], 1);
}

// ---- per-block exclusive prefix scan (one workgroup per block) ----
__global__ __launch_bounds__(1024) void scan_kernel(const int* __restrict__ deg,
                                                    int* __restrict__ offs,
                                                    int* __restrict__ cursor) {
  __shared__ int lds[1024];
  __shared__ int srun;
  int b = blockIdx.x;
  int s = b >> 2, d = b & 3;
  int nd = (s == d) ? NN : MM;
  int t = threadIdx.x;
  if (t == 0) srun = 0;
  __syncthreads();
  for (int base = 0; base < nd; base += 1024) {
    int val = deg[b * NN + base + t];
    lds[t] = val;
    __syncthreads();
    for (int off = 1; off < 1024; off <<= 1) {
      int x = (t >= off) ? lds[t - off] : 0;
      __syncthreads();
      lds[t] += x;
      __syncthreads();
    }
    int incl = lds[t];
    int run = srun;
    int ex = run + incl - val;
    offs[b * NN + base + t] = ex;
    cursor[b * NN + base + t] = ex;
    __syncthreads();
    if (t == 1023) srun = run + incl;
    __syncthreads();
  }
}

// ---- CSR bucket scatter ----
__global__ __launch_bounds__(256) void scatter_kernel(const int* __restrict__ esrc,
                                                      const int* __restrict__ edst,
                                                      int* __restrict__ cursor,
                                                      int* __restrict__ csr) {
  int b = blockIdx.y;
  int e = blockIdx.x * blockDim.x + threadIdx.x;
  if (e >= EE) return;
  int dv = edst[(size_t)b * EE + e];
  int p = atomicAdd(&cursor[b * NN + dv], 1);
  csr[(size_t)b * EE + p] = esrc[(size_t)b * EE + e];
}

// ---- mean aggregation: one wave per dst row, lane = bf16x2 column pair ----
__global__ __launch_bounds__(256) void agg_kernel(const unsigned short* __restrict__ featsbf,
                                                  const int* __restrict__ csr,
                                                  const int* __restrict__ offs,
                                                  const int* __restrict__ deg,
                                                  unsigned short* __restrict__ hbuf) {
  int b = blockIdx.y;
  int s = b >> 2, d = b & 3;
  int num_dst = (s == d) ? NN : MM;
  int v = blockIdx.x * 4 + (threadIdx.x >> 6);
  if (v >= num_dst) return;
  int l = threadIdx.x & 63;
  const unsigned* F = (const unsigned*)(featsbf + (size_t)s * NN * DD);
  int o = offs[b * NN + v];
  int dg = deg[b * NN + v];
  const int* cs = csr + (size_t)b * EE + o;
  float a0 = 0.f, a1 = 0.f;
  for (int j = 0; j < dg; ++j) {
    int idx = cs[j];
    unsigned p = F[(size_t)idx * 64 + l];
    a0 += bflo2f(p);
    a1 += bfhi2f(p);
  }
  float inv = 1.0f / (float)(dg > 0 ? dg : 1);
  a0 *= inv; a1 *= inv;
  unsigned pk = ((unsigned)f2bf(a1) << 16) | f2bf(a0);
  ((unsigned*)hbuf)[(rowbase(b) + v) * 64 + l] = pk;
}

// ---- fused dual GEMM + merge epilogue ----
// Workgroup: 256 thr = 4 waves; 64 rows x 128 cols per WG; wave w -> cols [32w,32w+32)
// mfma_f32_16x16x32_bf16: A[m=l&15][k=(l>>4)*8+j], B[k=(l>>4)*8+j][n=l&15],
//                         C col=l&15, row=(l>>4)*4+reg
__global__ __launch_bounds__(256) void gemm_kernel(const unsigned short* __restrict__ featsbf,
                                                   const unsigned short* __restrict__ hbuf,
                                                   const float* __restrict__ Wself,
                                                   const float* __restrict__ Wneigh,
                                                   const float* __restrict__ bias,
                                                   const int* __restrict__ merge,
                                                   float* __restrict__ out,
                                                   int offdiag) {
  int w = threadIdx.x >> 6;
  int l = threadIdx.x & 63;
  int s, d;
  if (!offdiag) { d = blockIdx.y; s = d; }
  else { int y = blockIdx.y; s = y / 3; int r = y % 3; d = r + (r >= s ? 1 : 0); }
  int b = s * 4 + d;
  int row0 = blockIdx.x * 64;
  int kq = l >> 4;
  int m16 = l & 15;
  int n0 = w * 32;

  const unsigned short* Aself = featsbf + (size_t)s * NN * DD;
  const unsigned short* Ah = hbuf + (size_t)rowbase(b) * DD;

  // B fragments in registers: [mat][kk][ntile], 8 bf16 each
  short8 bfrag[2][4][2];
  const float* Wm0 = Wself + (size_t)s * DD * OO;
  const float* Wm1 = Wneigh + (size_t)s * DD * OO;
#pragma unroll
  for (int mat = 0; mat < 2; ++mat) {
    const float* W = mat ? Wm1 : Wm0;
#pragma unroll
    for (int kk = 0; kk < 4; ++kk) {
#pragma unroll
      for (int t = 0; t < 2; ++t) {
        int col = n0 + 16 * t + m16;
        int kbase = kk * 32 + kq * 8;
        short8 bf;
#pragma unroll
        for (int j = 0; j < 8; ++j) bf[j] = (short)f2bf(W[(kbase + j) * OO + col]);
        bfrag[mat][kk][t] = bf;
      }
    }
  }

  floatx4 acc[4][2];
#pragma unroll
  for (int rt = 0; rt < 4; ++rt)
#pragma unroll
    for (int t = 0; t < 2; ++t) acc[rt][t] = (floatx4){0.f, 0.f, 0.f, 0.f};

#pragma unroll
  for (int mat = 0; mat < 2; ++mat) {
    const unsigned short* A = mat ? Ah : Aself;
#pragma unroll
    for (int kk = 0; kk < 4; ++kk) {
#pragma unroll
      for (int rt = 0; rt < 4; ++rt) {
        int row = row0 + rt * 16 + m16;
        short8 af = *reinterpret_cast<const short8*>(A + (size_t)row * DD + kk * 32 + kq * 8);
        acc[rt][0] = __builtin_amdgcn_mfma_f32_16x16x32_bf16(af, bfrag[mat][kk][0], acc[rt][0], 0, 0, 0);
        acc[rt][1] = __builtin_amdgcn_mfma_f32_16x16x32_bf16(af, bfrag[mat][kk][1], acc[rt][1], 0, 0, 0);
      }
    }
  }

  float bs0 = bias[s * OO + n0 + m16];
  float bs1 = bias[s * OO + n0 + 16 + m16];
  float* outd = out + (size_t)d * NN * OO;
  if (!offdiag) {
#pragma unroll
    for (int rt = 0; rt < 4; ++rt) {
#pragma unroll
      for (int r = 0; r < 4; ++r) {
        int row = row0 + rt * 16 + kq * 4 + r;
        outd[(size_t)row * OO + n0 + m16] = acc[rt][0][r] + bs0;
        outd[(size_t)row * OO + n0 + 16 + m16] = acc[rt][1][r] + bs1;
      }
    }
  } else {
    const int* mg = merge + ((size_t)s * PN + d) * MM;
#pragma unroll
    for (int rt = 0; rt < 4; ++rt) {
#pragma unroll
      for (int r = 0; r < 4; ++r) {
        int row = row0 + rt * 16 + kq * 4 + r;
        int u = mg[row];
        atomicAdd(&outd[(size_t)u * OO + n0 + m16], acc[rt][0][r] + bs0);
        atomicAdd(&outd[(size_t)u * OO + n0 + 16 + m16], acc[rt][1][r] + bs1);
      }
    }
  }
}

extern "C" void kernel_launch(void* const* d_in, const int* in_sizes, int n_in,
                              void* d_out, int out_size, void* d_ws, size_t ws_size,
                              hipStream_t stream) {
  const float* feats = (const float*)d_in[0];
  const float* Wself = (const float*)d_in[1];
  const float* Wneigh = (const float*)d_in[2];
  const float* bias = (const float*)d_in[3];
  const int* esrc = (const int*)d_in[4];
  const int* edst = (const int*)d_in[5];
  const int* merge = (const int*)d_in[6];
  float* out = (float*)d_out;

  char* ws = (char*)d_ws;
  unsigned short* featsbf = (unsigned short*)(ws);              // 67,108,864 B
  int* deg = (int*)(ws + 67108864);                             //  4,194,304 B
  int* offs = (int*)(ws + 71303168);                            //  4,194,304 B
  int* cursor = (int*)(ws + 75497472);                          //  4,194,304 B
  int* csr = (int*)(ws + 79691776);                             // 32,000,000 B
  unsigned short* hbuf = (unsigned short*)(ws + 111691776);     // 167,772,160 B  (total ~279.5 MB)

  hipMemsetAsync(deg, 0, 16 * NN * sizeof(int), stream);
  cvt_kernel<<<(PN * NN * DD) / 4 / 256, 256, 0, stream>>>(feats, featsbf);
  dim3 eg((EE + 255) / 256, 16);
  hist_kernel<<<eg, 256, 0, stream>>>(edst, deg);
  scan_kernel<<<16, 1024, 0, stream>>>(deg, offs, cursor);
  scatter_kernel<<<eg, 256, 0, stream>>>(esrc, edst, cursor, csr);
  agg_kernel<<<dim3(NN / 4, 16), 256, 0, stream>>>(featsbf, csr, offs, deg, hbuf);
  // diag first: plain writes cover all of d_out; then off-diag atomically merges
  gemm_kernel<<<dim3(NN / 64, 4), 256, 0, stream>>>(featsbf, hbuf, Wself, Wneigh, bias, merge, out, 0);
  gemm_kernel<<<dim3(MM / 64, 12), 256, 0, stream>>>(featsbf, hbuf, Wself, Wneigh, bias, merge, out, 1);
}

// Round 2
// 1311.106 us; speedup vs baseline: 1.7562x; 1.7562x over previous
//
#include <hip/hip_runtime.h>
#include <stdint.h>

#define PN 4
#define NN 65536
#define DD 128
#define OO 128
#define EE 500000
#define MM 32768

typedef __attribute__((ext_vector_type(8))) short short8;
typedef __attribute__((ext_vector_type(4))) float floatx4;

__device__ __forceinline__ unsigned short f2bf(float f) {
  unsigned u = __float_as_uint(f);
  u += 0x7fffu + ((u >> 16) & 1u);
  return (unsigned short)(u >> 16);
}
__device__ __forceinline__ float bfhi2f(unsigned u) { return __uint_as_float(u & 0xffff0000u); }
__device__ __forceinline__ float bflo2f(unsigned u) { return __uint_as_float(u << 16); }

// block b = s*4+d; diag blocks are b in {0,5,10,15}
__device__ __forceinline__ long rowbase(int b) {
  int diagb = (b + 4) / 5;
  int offb = b - diagb;
  return (long)diagb * NN + (long)offb * MM;
}

// ---- fp32 -> bf16 conversion of feats ----
__global__ __launch_bounds__(256) void cvt_kernel(const float* __restrict__ f,
                                                  unsigned short* __restrict__ o) {
  size_t i = (size_t)blockIdx.x * blockDim.x + threadIdx.x;
  float4 v = ((const float4*)f)[i];
  uint2 r;
  r.x = ((unsigned)f2bf(v.y) << 16) | f2bf(v.x);
  r.y = ((unsigned)f2bf(v.w) << 16) | f2bf(v.z);
  ((uint2*)o)[i] = r;
}

// ---- pack W_self/W_neigh to bf16, col-major [mat][s][col][k] ----
__global__ __launch_bounds__(256) void packW_kernel(const float* __restrict__ Ws,
                                                    const float* __restrict__ Wn,
                                                    unsigned short* __restrict__ Wp) {
  int i = blockIdx.x * 256 + threadIdx.x;   // 2*4*128*128 = 131072
  int k = i & 127;
  int col = (i >> 7) & 127;
  int s = (i >> 14) & 3;
  int mat = i >> 16;
  const float* W = mat ? Wn : Ws;
  Wp[i] = f2bf(W[((size_t)s * DD + k) * OO + col]);
}

// ---- in-degree histogram; atomic return value = edge rank within bucket ----
__global__ __launch_bounds__(256) void hist_kernel(const int* __restrict__ edst,
                                                   int* __restrict__ deg,
                                                   int* __restrict__ rank, int use_rank) {
  int b = blockIdx.y;
  int e = blockIdx.x * blockDim.x + threadIdx.x;
  if (e >= EE) return;
  int dv = edst[(size_t)b * EE + e];
  int r = atomicAdd(&deg[b * NN + dv], 1);
  if (use_rank) rank[(size_t)b * EE + e] = r;
}

// ---- 3-stage parallel exclusive scan over deg (per block b) ----
// stage A: per-1024-chunk sums
__global__ __launch_bounds__(256) void scanA_kernel(const int* __restrict__ deg,
                                                    int* __restrict__ csum) {
  int b = blockIdx.y, c = blockIdx.x;
  int nch = ((b >> 2) == (b & 3)) ? 64 : 32;
  if (c >= nch) return;
  int t = threadIdx.x;
  int4 v = ((const int4*)(deg + b * NN + c * 1024))[t];
  int sum = v.x + v.y + v.z + v.w;
  for (int off = 32; off; off >>= 1) sum += __shfl_down(sum, off);
  __shared__ int ws[4];
  if ((t & 63) == 0) ws[t >> 6] = sum;
  __syncthreads();
  if (t == 0) csum[b * 64 + c] = ws[0] + ws[1] + ws[2] + ws[3];
}
// stage B: one block, wave w scans block w's chunk sums
__global__ __launch_bounds__(1024) void scanB_kernel(const int* __restrict__ csum,
                                                     int* __restrict__ cofs) {
  int t = threadIdx.x;
  int b = t >> 6, l = t & 63;
  int nch = ((b >> 2) == (b & 3)) ? 64 : 32;
  int val = (l < nch) ? csum[b * 64 + l] : 0;
  int x = val;
  for (int off = 1; off < 64; off <<= 1) {
    int y = __shfl_up(x, off);
    if (l >= off) x += y;
  }
  cofs[b * 64 + l] = x - val;
}
// stage C: chunk-local scan + chunk offset -> offs
__global__ __launch_bounds__(256) void scanC_kernel(const int* __restrict__ deg,
                                                    const int* __restrict__ cofs,
                                                    int* __restrict__ offs) {
  int b = blockIdx.y, c = blockIdx.x;
  int nch = ((b >> 2) == (b & 3)) ? 64 : 32;
  if (c >= nch) return;
  int t = threadIdx.x, l = t & 63, w = t >> 6;
  int4 v = ((const int4*)(deg + b * NN + c * 1024))[t];
  int s4 = v.x + v.y + v.z + v.w;
  int x = s4;
  for (int off = 1; off < 64; off <<= 1) {
    int y = __shfl_up(x, off);
    if (l >= off) x += y;
  }
  __shared__ int wsum[4];
  if (l == 63) wsum[w] = x;
  __syncthreads();
  int wb = 0;
  for (int i = 0; i < w; ++i) wb += wsum[i];
  int ex = x - s4 + wb + cofs[b * 64 + c];
  int4 o;
  o.x = ex; o.y = ex + v.x; o.z = ex + v.x + v.y; o.w = ex + v.x + v.y + v.z;
  ((int4*)(offs + b * NN + c * 1024))[t] = o;
}

// ---- CSR bucket scatter (atomic-free when rank available) ----
__global__ __launch_bounds__(256) void scatter_kernel(const int* __restrict__ esrc,
                                                      const int* __restrict__ edst,
                                                      const int* __restrict__ offs,
                                                      int* __restrict__ cursor,
                                                      const int* __restrict__ rank,
                                                      int* __restrict__ csr, int use_rank) {
  int b = blockIdx.y;
  int e = blockIdx.x * blockDim.x + threadIdx.x;
  if (e >= EE) return;
  size_t i = (size_t)b * EE + e;
  int dv = edst[i];
  int p;
  if (use_rank) p = offs[b * NN + dv] + rank[i];
  else p = atomicAdd(&cursor[b * NN + dv], 1);
  csr[(size_t)b * EE + p] = esrc[i];
}

// ---- mean aggregation: one wave per dst row, ILP via shfl-broadcast + unroll ----
__global__ __launch_bounds__(256) void agg_kernel(const unsigned short* __restrict__ featsbf,
                                                  const int* __restrict__ csr,
                                                  const int* __restrict__ offs,
                                                  const int* __restrict__ deg,
                                                  unsigned short* __restrict__ hbuf) {
  int b = blockIdx.y;
  int s = b >> 2, d = b & 3;
  int num_dst = (s == d) ? NN : MM;
  int v = blockIdx.x * 4 + (threadIdx.x >> 6);
  if (v >= num_dst) return;
  int l = threadIdx.x & 63;
  const unsigned* F = (const unsigned*)(featsbf + (size_t)s * NN * DD);
  int o = offs[b * NN + v];
  int dg = deg[b * NN + v];
  const int* cs = csr + (size_t)b * EE + o;
  int dgc = dg < 64 ? dg : 64;
  int myidx = (l < dgc) ? cs[l] : 0;

  float alo[4] = {0.f, 0.f, 0.f, 0.f};
  float ahi[4] = {0.f, 0.f, 0.f, 0.f};
  int j = 0;
  for (; j + 8 <= dgc; j += 8) {
    int idx[8];
    unsigned p[8];
#pragma unroll
    for (int q = 0; q < 8; ++q) idx[q] = __shfl(myidx, j + q);
#pragma unroll
    for (int q = 0; q < 8; ++q) p[q] = F[(size_t)idx[q] * 64 + l];
#pragma unroll
    for (int q = 0; q < 8; ++q) { alo[q & 3] += bflo2f(p[q]); ahi[q & 3] += bfhi2f(p[q]); }
  }
  for (; j + 4 <= dgc; j += 4) {
    int idx[4];
    unsigned p[4];
#pragma unroll
    for (int q = 0; q < 4; ++q) idx[q] = __shfl(myidx, j + q);
#pragma unroll
    for (int q = 0; q < 4; ++q) p[q] = F[(size_t)idx[q] * 64 + l];
#pragma unroll
    for (int q = 0; q < 4; ++q) { alo[q] += bflo2f(p[q]); ahi[q] += bfhi2f(p[q]); }
  }
  for (; j < dgc; ++j) {
    unsigned p = F[(size_t)__shfl(myidx, j) * 64 + l];
    alo[0] += bflo2f(p); ahi[0] += bfhi2f(p);
  }
  for (; j < dg; ++j) {  // extremely rare (deg > 64)
    unsigned p = F[(size_t)cs[j] * 64 + l];
    alo[0] += bflo2f(p); ahi[0] += bfhi2f(p);
  }
  float a0 = (alo[0] + alo[1]) + (alo[2] + alo[3]);
  float a1 = (ahi[0] + ahi[1]) + (ahi[2] + ahi[3]);
  float inv = 1.0f / (float)(dg > 0 ? dg : 1);
  a0 *= inv; a1 *= inv;
  unsigned pk = ((unsigned)f2bf(a1) << 16) | f2bf(a0);
  ((unsigned*)hbuf)[(rowbase(b) + v) * 64 + l] = pk;
}

// ---- fused dual GEMM + merge epilogue ----
// mfma_f32_16x16x32_bf16: A[m=l&15][k=(l>>4)*8+j], B[k][n=l&15], C col=l&15, row=(l>>4)*4+reg
__global__ __launch_bounds__(256) void gemm_kernel(const unsigned short* __restrict__ featsbf,
                                                   const unsigned short* __restrict__ hbuf,
                                                   const unsigned short* __restrict__ Wpack,
                                                   const float* __restrict__ bias,
                                                   const int* __restrict__ merge,
                                                   float* __restrict__ out,
                                                   int offdiag) {
  int w = threadIdx.x >> 6;
  int l = threadIdx.x & 63;
  int s, d;
  if (!offdiag) { d = blockIdx.y; s = d; }
  else { int y = blockIdx.y; s = y / 3; int r = y % 3; d = r + (r >= s ? 1 : 0); }
  int b = s * 4 + d;
  int row0 = blockIdx.x * 64;
  int kq = l >> 4;
  int m16 = l & 15;
  int n0 = w * 32;

  const unsigned short* Aself = featsbf + (size_t)s * NN * DD;
  const unsigned short* Ah = hbuf + (size_t)rowbase(b) * DD;

  // B fragments from packed bf16 col-major W: contiguous 16B loads
  short8 bfrag[2][4][2];
#pragma unroll
  for (int mat = 0; mat < 2; ++mat) {
    const unsigned short* WT = Wpack + ((size_t)(mat * PN + s) * OO) * DD;
#pragma unroll
    for (int kk = 0; kk < 4; ++kk) {
#pragma unroll
      for (int t = 0; t < 2; ++t) {
        int col = n0 + 16 * t + m16;
        bfrag[mat][kk][t] =
            *reinterpret_cast<const short8*>(WT + (size_t)col * DD + kk * 32 + kq * 8);
      }
    }
  }

  floatx4 acc[4][2];
#pragma unroll
  for (int rt = 0; rt < 4; ++rt)
#pragma unroll
    for (int t = 0; t < 2; ++t) acc[rt][t] = (floatx4){0.f, 0.f, 0.f, 0.f};

#pragma unroll
  for (int mat = 0; mat < 2; ++mat) {
    const unsigned short* A = mat ? Ah : Aself;
#pragma unroll
    for (int kk = 0; kk < 4; ++kk) {
#pragma unroll
      for (int rt = 0; rt < 4; ++rt) {
        int row = row0 + rt * 16 + m16;
        short8 af = *reinterpret_cast<const short8*>(A + (size_t)row * DD + kk * 32 + kq * 8);
        acc[rt][0] = __builtin_amdgcn_mfma_f32_16x16x32_bf16(af, bfrag[mat][kk][0], acc[rt][0], 0, 0, 0);
        acc[rt][1] = __builtin_amdgcn_mfma_f32_16x16x32_bf16(af, bfrag[mat][kk][1], acc[rt][1], 0, 0, 0);
      }
    }
  }

  float bs0 = bias[s * OO + n0 + m16];
  float bs1 = bias[s * OO + n0 + 16 + m16];
  float* outd = out + (size_t)d * NN * OO;
  if (!offdiag) {
#pragma unroll
    for (int rt = 0; rt < 4; ++rt) {
#pragma unroll
      for (int r = 0; r < 4; ++r) {
        int row = row0 + rt * 16 + kq * 4 + r;
        outd[(size_t)row * OO + n0 + m16] = acc[rt][0][r] + bs0;
        outd[(size_t)row * OO + n0 + 16 + m16] = acc[rt][1][r] + bs1;
      }
    }
  } else {
    const int* mg = merge + ((size_t)s * PN + d) * MM;
#pragma unroll
    for (int rt = 0; rt < 4; ++rt) {
#pragma unroll
      for (int r = 0; r < 4; ++r) {
        int row = row0 + rt * 16 + kq * 4 + r;
        int u = mg[row];
        atomicAdd(&outd[(size_t)u * OO + n0 + m16], acc[rt][0][r] + bs0);
        atomicAdd(&outd[(size_t)u * OO + n0 + 16 + m16], acc[rt][1][r] + bs1);
      }
    }
  }
}

extern "C" void kernel_launch(void* const* d_in, const int* in_sizes, int n_in,
                              void* d_out, int out_size, void* d_ws, size_t ws_size,
                              hipStream_t stream) {
  const float* feats = (const float*)d_in[0];
  const float* Wself = (const float*)d_in[1];
  const float* Wneigh = (const float*)d_in[2];
  const float* bias = (const float*)d_in[3];
  const int* esrc = (const int*)d_in[4];
  const int* edst = (const int*)d_in[5];
  const int* merge = (const int*)d_in[6];
  float* out = (float*)d_out;

  char* ws = (char*)d_ws;
  unsigned short* featsbf = (unsigned short*)(ws);               // 67,108,864
  int* deg   = (int*)(ws + 67108864);                            //  4,194,304
  int* offs  = (int*)(ws + 71303168);                            //  4,194,304
  int* csr   = (int*)(ws + 75497472);                            // 32,000,000
  unsigned short* hbuf = (unsigned short*)(ws + 107497472);      // 167,772,160
  unsigned short* Wpack = (unsigned short*)(ws + 275269632);     //    262,144
  int* csum  = (int*)(ws + 275531776);                           //      4,096
  int* cofs  = (int*)(ws + 275535872);                           //      4,096
  // tail region: rank (32,000,000) if it fits, else cursor (4,194,304)
  int* rank   = (int*)(ws + 275539968);
  int* cursor = (int*)(ws + 275539968);
  int use_rank = (ws_size >= (size_t)275539968 + 32000000) ? 1 : 0;

  hipMemsetAsync(deg, 0, 16 * NN * sizeof(int), stream);
  cvt_kernel<<<(PN * NN * DD) / 4 / 256, 256, 0, stream>>>(feats, featsbf);
  packW_kernel<<<512, 256, 0, stream>>>(Wself, Wneigh, Wpack);
  dim3 eg((EE + 255) / 256, 16);
  hist_kernel<<<eg, 256, 0, stream>>>(edst, deg, rank, use_rank);
  scanA_kernel<<<dim3(64, 16), 256, 0, stream>>>(deg, csum);
  scanB_kernel<<<1, 1024, 0, stream>>>(csum, cofs);
  scanC_kernel<<<dim3(64, 16), 256, 0, stream>>>(deg, cofs, offs);
  if (!use_rank)
    hipMemcpyAsync(cursor, offs, 16 * NN * sizeof(int), hipMemcpyDeviceToDevice, stream);
  scatter_kernel<<<eg, 256, 0, stream>>>(esrc, edst, offs, cursor, rank, csr, use_rank);
  agg_kernel<<<dim3(NN / 4, 16), 256, 0, stream>>>(featsbf, csr, offs, deg, hbuf);
  // diag first: plain writes cover all of d_out; then off-diag atomically merges
  gemm_kernel<<<dim3(NN / 64, 4), 256, 0, stream>>>(featsbf, hbuf, Wpack, bias, merge, out, 0);
  gemm_kernel<<<dim3(MM / 64, 12), 256, 0, stream>>>(featsbf, hbuf, Wpack, bias, merge, out, 1);
}

// Round 3
// 1042.240 us; speedup vs baseline: 2.2092x; 1.2580x over previous
//
#include <hip/hip_runtime.h>
#include <stdint.h>

#define PN 4
#define NN 65536
#define DD 128
#define OO 128
#define EE 500000
#define MM 32768
#define NW 245       // WGs per block for bucketing: ceil(500000/2048)

typedef __attribute__((ext_vector_type(8))) short short8;
typedef __attribute__((ext_vector_type(4))) float floatx4;

__device__ __forceinline__ unsigned short f2bf(float f) {
  unsigned u = __float_as_uint(f);
  u += 0x7fffu + ((u >> 16) & 1u);
  return (unsigned short)(u >> 16);
}
__device__ __forceinline__ float bfhi2f(unsigned u) { return __uint_as_float(u & 0xffff0000u); }
__device__ __forceinline__ float bflo2f(unsigned u) { return __uint_as_float(u << 16); }

// block b = s*4+d; diag blocks are b in {0,5,10,15}
__device__ __forceinline__ long rowbase(int b) {
  int diagb = (b + 4) / 5;
  int offb = b - diagb;
  return (long)diagb * NN + (long)offb * MM;
}

// ---- fp32 -> bf16 conversion of feats ----
__global__ __launch_bounds__(256) void cvt_kernel(const float* __restrict__ f,
                                                  unsigned short* __restrict__ o) {
  size_t i = (size_t)blockIdx.x * blockDim.x + threadIdx.x;
  float4 v = ((const float4*)f)[i];
  uint2 r;
  r.x = ((unsigned)f2bf(v.y) << 16) | f2bf(v.x);
  r.y = ((unsigned)f2bf(v.w) << 16) | f2bf(v.z);
  ((uint2*)o)[i] = r;
}

// ---- pack W_self/W_neigh to bf16, col-major [mat][s][col][k] ----
__global__ __launch_bounds__(256) void packW_kernel(const float* __restrict__ Ws,
                                                    const float* __restrict__ Wn,
                                                    unsigned short* __restrict__ Wp) {
  int i = blockIdx.x * 256 + threadIdx.x;   // 2*4*128*128 = 131072
  int k = i & 127;
  int col = (i >> 7) & 127;
  int s = (i >> 14) & 3;
  int mat = i >> 16;
  const float* W = mat ? Wn : Ws;
  Wp[i] = f2bf(W[((size_t)s * DD + k) * OO + col]);
}

// ---- R1: per-WG coarse histogram (dst>>8), LDS only, coalesced matrix write ----
__global__ __launch_bounds__(256) void bucket_count(const int* __restrict__ edst,
                                                    int* __restrict__ mat) {
  __shared__ int hist[256];
  int b = blockIdx.y, w = blockIdx.x, t = threadIdx.x;
  hist[t] = 0;
  __syncthreads();
  size_t ebase = (size_t)b * EE;
#pragma unroll
  for (int k = 0; k < 8; ++k) {
    int e = w * 2048 + k * 256 + t;
    if (e < EE) atomicAdd(&hist[edst[ebase + e] >> 8], 1);
  }
  __syncthreads();
  mat[((size_t)b * NW + w) * 256 + t] = hist[t];
}

// ---- R2a: exclusive scan of mat over WG axis (per b,beta); totals per bucket ----
__global__ __launch_bounds__(256) void bucket_colscan(int* __restrict__ mat,
                                                      int* __restrict__ btot) {
  int t = threadIdx.x;
  int wid = blockIdx.x * 4 + (t >> 6);   // 4096 waves = 16 b * 256 beta
  int l = t & 63;
  int b = wid >> 8, beta = wid & 255;
  int run = 0;
  for (int c = 0; c < 4; ++c) {
    int w = c * 64 + l;
    size_t idx = ((size_t)b * NW + w) * 256 + beta;
    int v = (w < NW) ? mat[idx] : 0;
    int x = v;
#pragma unroll
    for (int off = 1; off < 64; off <<= 1) {
      int y = __shfl_up(x, off);
      if (l >= off) x += y;
    }
    if (w < NW) mat[idx] = run + x - v;
    run += __shfl(x, 63);
  }
  if (l == 0) btot[b * 256 + beta] = run;
}

// ---- R2b: per-block exclusive scan of 256 bucket totals -> bucket bases ----
__global__ __launch_bounds__(256) void bucket_base(const int* __restrict__ btot,
                                                   int* __restrict__ bbase) {
  __shared__ int sc[256];
  int b = blockIdx.x, t = threadIdx.x;
  int v = btot[b * 256 + t];
  sc[t] = v;
  __syncthreads();
  for (int off = 1; off < 256; off <<= 1) {
    int x = (t >= off) ? sc[t - off] : 0;
    __syncthreads();
    sc[t] += x;
    __syncthreads();
  }
  bbase[b * 256 + t] = sc[t] - v;
}

// ---- R3: scatter edges into coarse-bucket-sorted tmp via LDS cursors ----
__global__ __launch_bounds__(256) void bucket_scatter(const int* __restrict__ esrc,
                                                      const int* __restrict__ edst,
                                                      const int* __restrict__ mat,
                                                      const int* __restrict__ bbase,
                                                      uint2* __restrict__ tmp) {
  __shared__ int cur[256];
  int b = blockIdx.y, w = blockIdx.x, t = threadIdx.x;
  cur[t] = bbase[b * 256 + t] + mat[((size_t)b * NW + w) * 256 + t];
  __syncthreads();
  size_t ebase = (size_t)b * EE;
#pragma unroll
  for (int k = 0; k < 8; ++k) {
    int e = w * 2048 + k * 256 + t;
    if (e < EE) {
      int dv = edst[ebase + e];
      int sv = esrc[ebase + e];
      int p = atomicAdd(&cur[dv >> 8], 1);
      tmp[ebase + p] = (uint2){(unsigned)dv, (unsigned)sv};
    }
  }
}

// ---- R4: per (b, coarse bucket): fine CSR + deg + offs, all LDS-local ----
__global__ __launch_bounds__(256) void csr_build(const uint2* __restrict__ tmp,
                                                 const int* __restrict__ btot,
                                                 const int* __restrict__ bbase,
                                                 int* __restrict__ deg,
                                                 int* __restrict__ offs,
                                                 int* __restrict__ csr) {
  __shared__ int hist[256], sc[256], cur[256];
  int b = blockIdx.y, beta = blockIdx.x, t = threadIdx.x;
  int cnt = btot[b * 256 + beta];
  int segbase = bbase[b * 256 + beta];
  hist[t] = 0;
  __syncthreads();
  size_t tbase = (size_t)b * EE + segbase;
  for (int i = t; i < cnt; i += 256) atomicAdd(&hist[tmp[tbase + i].x & 255], 1);
  __syncthreads();
  sc[t] = hist[t];
  __syncthreads();
  for (int off = 1; off < 256; off <<= 1) {
    int x = (t >= off) ? sc[t - off] : 0;
    __syncthreads();
    sc[t] += x;
    __syncthreads();
  }
  int excl = sc[t] - hist[t];
  int v = beta * 256 + t;
  deg[b * NN + v] = hist[t];
  offs[b * NN + v] = segbase + excl;
  cur[t] = excl;
  __syncthreads();
  for (int i = t; i < cnt; i += 256) {
    uint2 pr = tmp[tbase + i];
    int p = atomicAdd(&cur[pr.x & 255], 1);
    csr[(size_t)b * EE + segbase + p] = (int)pr.y;
  }
}

// ---- mean aggregation: one wave per dst row, ILP via shfl-broadcast + unroll ----
__global__ __launch_bounds__(256) void agg_kernel(const unsigned short* __restrict__ featsbf,
                                                  const int* __restrict__ csr,
                                                  const int* __restrict__ offs,
                                                  const int* __restrict__ deg,
                                                  unsigned short* __restrict__ hbuf) {
  int b = blockIdx.y;
  int s = b >> 2, d = b & 3;
  int num_dst = (s == d) ? NN : MM;
  int v = blockIdx.x * 4 + (threadIdx.x >> 6);
  if (v >= num_dst) return;
  int l = threadIdx.x & 63;
  const unsigned* F = (const unsigned*)(featsbf + (size_t)s * NN * DD);
  int o = offs[b * NN + v];
  int dg = deg[b * NN + v];
  const int* cs = csr + (size_t)b * EE + o;
  int dgc = dg < 64 ? dg : 64;
  int myidx = (l < dgc) ? cs[l] : 0;

  float alo[4] = {0.f, 0.f, 0.f, 0.f};
  float ahi[4] = {0.f, 0.f, 0.f, 0.f};
  int j = 0;
  for (; j + 8 <= dgc; j += 8) {
    int idx[8];
    unsigned p[8];
#pragma unroll
    for (int q = 0; q < 8; ++q) idx[q] = __shfl(myidx, j + q);
#pragma unroll
    for (int q = 0; q < 8; ++q) p[q] = F[(size_t)idx[q] * 64 + l];
#pragma unroll
    for (int q = 0; q < 8; ++q) { alo[q & 3] += bflo2f(p[q]); ahi[q & 3] += bfhi2f(p[q]); }
  }
  for (; j + 4 <= dgc; j += 4) {
    int idx[4];
    unsigned p[4];
#pragma unroll
    for (int q = 0; q < 4; ++q) idx[q] = __shfl(myidx, j + q);
#pragma unroll
    for (int q = 0; q < 4; ++q) p[q] = F[(size_t)idx[q] * 64 + l];
#pragma unroll
    for (int q = 0; q < 4; ++q) { alo[q] += bflo2f(p[q]); ahi[q] += bfhi2f(p[q]); }
  }
  for (; j < dgc; ++j) {
    unsigned p = F[(size_t)__shfl(myidx, j) * 64 + l];
    alo[0] += bflo2f(p); ahi[0] += bfhi2f(p);
  }
  for (; j < dg; ++j) {  // rare (deg > 64)
    unsigned p = F[(size_t)cs[j] * 64 + l];
    alo[0] += bflo2f(p); ahi[0] += bfhi2f(p);
  }
  float a0 = (alo[0] + alo[1]) + (alo[2] + alo[3]);
  float a1 = (ahi[0] + ahi[1]) + (ahi[2] + ahi[3]);
  float inv = 1.0f / (float)(dg > 0 ? dg : 1);
  a0 *= inv; a1 *= inv;
  unsigned pk = ((unsigned)f2bf(a1) << 16) | f2bf(a0);
  ((unsigned*)hbuf)[(rowbase(b) + v) * 64 + l] = pk;
}

// ---- fused dual GEMM + merge epilogue ----
// mfma_f32_16x16x32_bf16: A[m=l&15][k=(l>>4)*8+j], B[k][n=l&15], C col=l&15, row=(l>>4)*4+reg
__global__ __launch_bounds__(256) void gemm_kernel(const unsigned short* __restrict__ featsbf,
                                                   const unsigned short* __restrict__ hbuf,
                                                   const unsigned short* __restrict__ Wpack,
                                                   const float* __restrict__ bias,
                                                   const int* __restrict__ merge,
                                                   float* __restrict__ out,
                                                   int offdiag) {
  int w = threadIdx.x >> 6;
  int l = threadIdx.x & 63;
  int s, d;
  if (!offdiag) { d = blockIdx.y; s = d; }
  else { int y = blockIdx.y; s = y / 3; int r = y % 3; d = r + (r >= s ? 1 : 0); }
  int b = s * 4 + d;
  int row0 = blockIdx.x * 64;
  int kq = l >> 4;
  int m16 = l & 15;
  int n0 = w * 32;

  const unsigned short* Aself = featsbf + (size_t)s * NN * DD;
  const unsigned short* Ah = hbuf + (size_t)rowbase(b) * DD;

  short8 bfrag[2][4][2];
#pragma unroll
  for (int mat = 0; mat < 2; ++mat) {
    const unsigned short* WT = Wpack + ((size_t)(mat * PN + s) * OO) * DD;
#pragma unroll
    for (int kk = 0; kk < 4; ++kk) {
#pragma unroll
      for (int t = 0; t < 2; ++t) {
        int col = n0 + 16 * t + m16;
        bfrag[mat][kk][t] =
            *reinterpret_cast<const short8*>(WT + (size_t)col * DD + kk * 32 + kq * 8);
      }
    }
  }

  floatx4 acc[4][2];
#pragma unroll
  for (int rt = 0; rt < 4; ++rt)
#pragma unroll
    for (int t = 0; t < 2; ++t) acc[rt][t] = (floatx4){0.f, 0.f, 0.f, 0.f};

#pragma unroll
  for (int mat = 0; mat < 2; ++mat) {
    const unsigned short* A = mat ? Ah : Aself;
#pragma unroll
    for (int kk = 0; kk < 4; ++kk) {
#pragma unroll
      for (int rt = 0; rt < 4; ++rt) {
        int row = row0 + rt * 16 + m16;
        short8 af = *reinterpret_cast<const short8*>(A + (size_t)row * DD + kk * 32 + kq * 8);
        acc[rt][0] = __builtin_amdgcn_mfma_f32_16x16x32_bf16(af, bfrag[mat][kk][0], acc[rt][0], 0, 0, 0);
        acc[rt][1] = __builtin_amdgcn_mfma_f32_16x16x32_bf16(af, bfrag[mat][kk][1], acc[rt][1], 0, 0, 0);
      }
    }
  }

  float bs0 = bias[s * OO + n0 + m16];
  float bs1 = bias[s * OO + n0 + 16 + m16];
  float* outd = out + (size_t)d * NN * OO;
  if (!offdiag) {
#pragma unroll
    for (int rt = 0; rt < 4; ++rt) {
#pragma unroll
      for (int r = 0; r < 4; ++r) {
        int row = row0 + rt * 16 + kq * 4 + r;
        outd[(size_t)row * OO + n0 + m16] = acc[rt][0][r] + bs0;
        outd[(size_t)row * OO + n0 + 16 + m16] = acc[rt][1][r] + bs1;
      }
    }
  } else {
    const int* mg = merge + ((size_t)s * PN + d) * MM;
#pragma unroll
    for (int rt = 0; rt < 4; ++rt) {
#pragma unroll
      for (int r = 0; r < 4; ++r) {
        int row = row0 + rt * 16 + kq * 4 + r;
        int u = mg[row];
        atomicAdd(&outd[(size_t)u * OO + n0 + m16], acc[rt][0][r] + bs0);
        atomicAdd(&outd[(size_t)u * OO + n0 + 16 + m16], acc[rt][1][r] + bs1);
      }
    }
  }
}

extern "C" void kernel_launch(void* const* d_in, const int* in_sizes, int n_in,
                              void* d_out, int out_size, void* d_ws, size_t ws_size,
                              hipStream_t stream) {
  const float* feats = (const float*)d_in[0];
  const float* Wself = (const float*)d_in[1];
  const float* Wneigh = (const float*)d_in[2];
  const float* bias = (const float*)d_in[3];
  const int* esrc = (const int*)d_in[4];
  const int* edst = (const int*)d_in[5];
  const int* merge = (const int*)d_in[6];
  float* out = (float*)d_out;

  char* ws = (char*)d_ws;
  unsigned short* featsbf = (unsigned short*)(ws);               // 67,108,864
  int* deg   = (int*)(ws + 67108864);                            //  4,194,304
  int* offs  = (int*)(ws + 71303168);                            //  4,194,304
  int* csr   = (int*)(ws + 75497472);                            // 32,000,000
  unsigned short* hbuf = (unsigned short*)(ws + 107497472);      // 167,772,160 (ends 275,269,632)
  unsigned short* Wpack = (unsigned short*)(ws + 275269632);     //     262,144
  int* btot  = (int*)(ws + 275531776);                           //      16,384
  int* bbase = (int*)(ws + 275548160);                           //      16,384 (total 275,564,544)
  // overlays inside hbuf region (consumed before agg writes hbuf):
  uint2* tmp = (uint2*)(ws + 107497472);                         //  64,000,000
  int* mat   = (int*)(ws + 107497472 + 64000000);                //  16,056,320

  cvt_kernel<<<(PN * NN * DD) / 4 / 256, 256, 0, stream>>>(feats, featsbf);
  packW_kernel<<<512, 256, 0, stream>>>(Wself, Wneigh, Wpack);
  bucket_count<<<dim3(NW, 16), 256, 0, stream>>>(edst, mat);
  bucket_colscan<<<1024, 256, 0, stream>>>(mat, btot);
  bucket_base<<<16, 256, 0, stream>>>(btot, bbase);
  bucket_scatter<<<dim3(NW, 16), 256, 0, stream>>>(esrc, edst, mat, bbase, tmp);
  csr_build<<<dim3(256, 16), 256, 0, stream>>>(tmp, btot, bbase, deg, offs, csr);
  agg_kernel<<<dim3(NN / 4, 16), 256, 0, stream>>>(featsbf, csr, offs, deg, hbuf);
  // diag first: plain writes cover all of d_out; then off-diag atomically merges
  gemm_kernel<<<dim3(NN / 64, 4), 256, 0, stream>>>(featsbf, hbuf, Wpack, bias, merge, out, 0);
  gemm_kernel<<<dim3(MM / 64, 12), 256, 0, stream>>>(featsbf, hbuf, Wpack, bias, merge, out, 1);
}